// Round 12
// baseline (55.179 us; speedup 1.0000x reference)
//
#include <hip/hip_runtime.h>

// KNN (k=16) within batch-diagonal blocks + neighbor-feature mean-pool.
// N = 16384 points, 8 batches of 2048 (contiguous), FEAT = 16.
//
// R11 -> R12: full register cache of all 32 per-lane candidates as mono(d2)
// u32 keys (order-isomorphic to d2: umin + threshold compare run in key
// domain; cached bits ARE the phase-A bits => exactness unchanged).
//  * Phase B: pure in-register ballot loop — zero loads, zero recompute.
//  * Phase A fully unrolled: 32 independent dwordx4 loads hoisted by the
//    compiler (deep vmcnt pipelining, L2-hot).
//  * __launch_bounds__(512,7): cap ~72 regs; need ~56-60 (R9's spill was
//    the cap-64 bound of (512,8), not the cache idea).
// Exactness machinery unchanged (10 passing rounds): reference-bit d2
// (FMA chain, rounded squares), thr = 16th-smallest of 64 lane-mins
// (provably valid), u64 (mono(d2)<<32|idx) keys == lax.top_k stable order,
// butterfly mean rounding relaxation (proven R4+).

typedef unsigned long long u64;
typedef unsigned int u32;

#define FEAT 16
#define BLK_WAVES 8
#define THREADS (BLK_WAVES * 64)   // 512
#define LIST_CAP 512
#define INF_KEY 0xFFFFFFFFFFFFFFFFull

__global__ void knn_prep(const float* __restrict__ y, float4* __restrict__ yp, int m)
{
    const int j = blockIdx.x * 256 + (int)threadIdx.x;
    if (j < m) {
        const float a0 = y[(size_t)j * 3 + 0];
        const float a1 = y[(size_t)j * 3 + 1];
        const float a2 = y[(size_t)j * 3 + 2];
        const float s  = __fadd_rn(__fadd_rn(__fmul_rn(a0, a0), __fmul_rn(a1, a1)),
                                   __fmul_rn(a2, a2));
        yp[j] = make_float4(a0, a1, a2, s);
    }
}

__device__ __forceinline__ u32 mono(float f) {
    const u32 b = __float_as_uint(f);
    return b ^ (((u32)(((int)b) >> 31)) | 0x80000000u);
}
__device__ __forceinline__ int lanes_below(u64 mask) {
    return __builtin_amdgcn_mbcnt_hi((u32)(mask >> 32),
           __builtin_amdgcn_mbcnt_lo((u32)mask, 0));
}

// Cross-lane bitonic sort over the 64 lanes, ascending by lane index.
__device__ __forceinline__ u32 sort64_u32(u32 k, int lane) {
#pragma unroll
    for (int kk = 2; kk <= 64; kk <<= 1) {
#pragma unroll
        for (int j = kk >> 1; j > 0; j >>= 1) {
            const u32 o = __shfl_xor(k, j);
            const bool keep_min = (((lane & j) == 0) == ((lane & kk) == 0));
            const u32 mn = (k < o) ? k : o;
            const u32 mx = (k < o) ? o : k;
            k = keep_min ? mn : mx;
        }
    }
    return k;
}
__device__ __forceinline__ u64 sort64_u64(u64 k, int lane) {
#pragma unroll
    for (int kk = 2; kk <= 64; kk <<= 1) {
#pragma unroll
        for (int j = kk >> 1; j > 0; j >>= 1) {
            const u64 o = __shfl_xor(k, j);
            const bool keep_min = (((lane & j) == 0) == ((lane & kk) == 0));
            const u64 mn = (k < o) ? k : o;
            const u64 mx = (k < o) ? o : k;
            k = keep_min ? mn : mx;
        }
    }
    return k;
}

// TOTC > 0: compile-time per-lane candidate count, all register-cached as
// mono keys. TOTC == 0: generic runtime fallback (R8 two-pass structure).
template <int TOTC>
__global__ __launch_bounds__(THREADS, 7) void knn_main(
    const float* __restrict__ x, const float4* __restrict__ yp,
    const float* __restrict__ y, const float* __restrict__ feat,
    const int* __restrict__ x_batch, float* __restrict__ out,
    int n, int per, int packed)
{
    __shared__ u64 list_s[BLK_WAVES][LIST_CAP];  // 32 KiB survivor lists

    const int lane = (int)threadIdx.x & 63;
    const int wv   = (int)(threadIdx.x >> 6);
    const int i    = blockIdx.x * BLK_WAVES + wv;   // this wave's point
    if (i >= n) return;

    const int b     = x_batch[i];                   // lane-uniform
    const int ybase = b * per;

    const float px0 = x[(size_t)i * 3 + 0];
    const float px1 = x[(size_t)i * 3 + 1];
    const float px2 = x[(size_t)i * 3 + 2];
    const float x2s = __fadd_rn(__fadd_rn(__fmul_rn(px0, px0), __fmul_rn(px1, px1)),
                                __fmul_rn(px2, px2));

    int S = 0;                                      // wave-uniform count

    if constexpr (TOTC > 0) {
        // ---- Phase A: mono(d2) for candidates j = ybase + t*64 + lane,
        // fully cached in registers (u32 keys; order-isomorphic to d2).
        u32 kc[TOTC];
        u32 mk0 = 0xFFFFFFFFu, mk1 = 0xFFFFFFFFu;
#pragma unroll
        for (int t = 0; t < TOTC; ++t) {
            const float4 q = yp[ybase + t * 64 + lane];   // coalesced
            float dot = __fmaf_rn(px0, q.x, 0.0f);
            dot = __fmaf_rn(px1, q.y, dot);
            dot = __fmaf_rn(px2, q.z, dot);
            const float d2 = __fsub_rn(__fadd_rn(x2s, q.w), __fmul_rn(2.0f, dot));
            const u32 k = mono(d2);
            kc[t] = k;
            if (t & 1) mk1 = (k < mk1) ? k : mk1;
            else       mk0 = (k < mk0) ? k : mk0;
        }
        const u32 mk = (mk0 < mk1) ? mk0 : mk1;

        // thr key = 16th-smallest of the 64 lane-min keys (exact bits).
        const u32 sorted = sort64_u32(mk, lane);
        const u32 thrk = __shfl(sorted, 15);

        // ---- Phase B: in-register ballot-compacted append (no loads).
#pragma unroll
        for (int t = 0; t < TOTC; ++t) {
            const bool pred = (kc[t] <= thrk);
            const u64 mask = __ballot(pred);
            if (pred) {
                const int slot = S + lanes_below(mask);
                if (slot < LIST_CAP)
                    list_s[wv][slot] =
                        ((u64)kc[t] << 32) | (u32)(ybase + t * 64 + lane);
            }
            S += __popcll(mask);
        }
    } else {
        // Generic fallback: two-pass scan (R8 structure, unpacked y ok).
        const int iters = per / 64;
        float md = __builtin_inff();
        for (int t = 0; t < iters; ++t) {
            const int j = ybase + t * 64 + lane;
            float q0, q1, q2, qs;
            if (packed) {
                const float4 q = yp[j];
                q0 = q.x; q1 = q.y; q2 = q.z; qs = q.w;
            } else {
                q0 = y[(size_t)j * 3 + 0];
                q1 = y[(size_t)j * 3 + 1];
                q2 = y[(size_t)j * 3 + 2];
                qs = __fadd_rn(__fadd_rn(__fmul_rn(q0, q0), __fmul_rn(q1, q1)),
                               __fmul_rn(q2, q2));
            }
            float dot = __fmaf_rn(px0, q0, 0.0f);
            dot = __fmaf_rn(px1, q1, dot);
            dot = __fmaf_rn(px2, q2, dot);
            md = fminf(md, __fsub_rn(__fadd_rn(x2s, qs), __fmul_rn(2.0f, dot)));
        }
        const u32 sorted = sort64_u32(mono(md), lane);
        const u32 thrk = __shfl(sorted, 15);
        for (int t = 0; t < iters; ++t) {
            const int j = ybase + t * 64 + lane;
            float q0, q1, q2, qs;
            if (packed) {
                const float4 q = yp[j];
                q0 = q.x; q1 = q.y; q2 = q.z; qs = q.w;
            } else {
                q0 = y[(size_t)j * 3 + 0];
                q1 = y[(size_t)j * 3 + 1];
                q2 = y[(size_t)j * 3 + 2];
                qs = __fadd_rn(__fadd_rn(__fmul_rn(q0, q0), __fmul_rn(q1, q1)),
                               __fmul_rn(q2, q2));
            }
            float dot = __fmaf_rn(px0, q0, 0.0f);
            dot = __fmaf_rn(px1, q1, dot);
            dot = __fmaf_rn(px2, q2, dot);
            const u32 k = mono(__fsub_rn(__fadd_rn(x2s, qs), __fmul_rn(2.0f, dot)));
            const bool pred = (k <= thrk);
            const u64 mask = __ballot(pred);
            if (pred) {
                const int slot = S + lanes_below(mask);
                if (slot < LIST_CAP)
                    list_s[wv][slot] = ((u64)k << 32) | (u32)j;
            }
            S += __popcll(mask);
        }
    }

    if (S > LIST_CAP) S = LIST_CAP;

    // ---- Phase C: top-16 via wave sort-64 (chunked for S > 64; exact).
    u64 k0 = (lane < S) ? list_s[wv][lane] : INF_KEY;
    u64 top = sort64_u64(k0, lane);
    for (int pos = 64; pos < S; pos += 48) {
        const int src = pos + lane - 16;
        const u64 k = (lane < 16) ? top
                                  : ((src < S) ? list_s[wv][src] : INF_KEY);
        top = sort64_u64(k, lane);
    }

    // ---- Gather + mean, all 64 lanes: rank = lane&15, chunk = lane>>4.
    const int r = lane & 15;
    const int c = lane >> 4;
    const u64 krank = __shfl(top, r);               // rank-r key (lanes 0..15)
    const int gidx  = (int)(u32)krank;              // global y index
    const float4 fq = ((const float4*)feat)[(size_t)gidx * 4 + c];
    float f0 = fq.x, f1 = fq.y, f2 = fq.z, f3 = fq.w;
#pragma unroll
    for (int mask = 1; mask <= 8; mask <<= 1) {     // sum over ranks in-group
        f0 = __fadd_rn(f0, __shfl_xor(f0, mask));
        f1 = __fadd_rn(f1, __shfl_xor(f1, mask));
        f2 = __fadd_rn(f2, __shfl_xor(f2, mask));
        f3 = __fadd_rn(f3, __shfl_xor(f3, mask));
    }
    if (r == 0) {
        float4* o4 = (float4*)out + (size_t)i * 4;
        o4[c] = make_float4(__fmul_rn(f0, 0.0625f), __fmul_rn(f1, 0.0625f),
                            __fmul_rn(f2, 0.0625f), __fmul_rn(f3, 0.0625f));
    }
}

extern "C" void kernel_launch(void* const* d_in, const int* in_sizes, int n_in,
                              void* d_out, int out_size, void* d_ws, size_t ws_size,
                              hipStream_t stream) {
    const float* x       = (const float*)d_in[0];
    const float* y       = (const float*)d_in[1];
    const float* feat    = (const float*)d_in[2];
    const int*   x_batch = (const int*)d_in[3];

    const int n   = in_sizes[0] / 3;   // 16384 query points
    const int m   = in_sizes[1] / 3;   // 16384 y points
    const int per = m / 8;             // 2048 per batch (N_BATCHES = 8)

    float* out = (float*)d_out;

    const size_t need = (size_t)m * sizeof(float4);
    const int packed = (ws_size >= need) ? 1 : 0;
    float4* yp = (float4*)d_ws;

    if (packed)
        knn_prep<<<(m + 255) / 256, 256, 0, stream>>>(y, yp, m);

    const int blocks = (n + BLK_WAVES - 1) / BLK_WAVES;   // 2048
    if (packed && per == 2048)
        knn_main<32><<<blocks, THREADS, 0, stream>>>(x, yp, y, feat,
                                                     x_batch, out, n, per, packed);
    else
        knn_main<0><<<blocks, THREADS, 0, stream>>>(x, yp, y, feat,
                                                    x_batch, out, n, per, packed);
}